// Round 1
// baseline (776.950 us; speedup 1.0000x reference)
//
#include <hip/hip_runtime.h>
#include <math.h>

#define BB 8
#define HH 448
#define WW 1024
#define HWSZ (HH*WW)
#define NPIX (BB*HH*WW)
#define CR 3
#define TX 64
#define TY 16
#define HX (TX+2*CR)   // 70
#define HY (TY+2*CR)   // 22

// acc layout (floats in ws): [0]=census_sum [1]=smooth_x_sum [2]=smooth_y_sum [3]=epe_sum

__global__ __launch_bounds__(256) void k_prep(
    const float* __restrict__ flow, const float* __restrict__ target,
    const float* __restrict__ img1, const float* __restrict__ img2,
    float* __restrict__ g1, float* __restrict__ g2, float* __restrict__ acc)
{
    const int x = blockIdx.x * 64 + threadIdx.x;
    const int y = blockIdx.y * 4 + threadIdx.y;
    const int b = blockIdx.z;
    const int idx = y * WW + x;
    const float* i1 = img1 + (size_t)b * 3 * HWSZ;
    const float* i2 = img2 + (size_t)b * 3 * HWSZ;
    const float* fl = flow + (size_t)b * 2 * HWSZ;
    const float* tg = target + (size_t)b * 2 * HWSZ;

    float r1 = i1[idx], q1 = i1[HWSZ + idx], b1 = i1[2 * HWSZ + idx];
    float r2 = i2[idx], q2 = i2[HWSZ + idx], b2 = i2[2 * HWSZ + idx];
    float lum1 = (0.299f * r1 + 0.587f * q1 + 0.114f * b1) * 255.0f;
    float lum2 = (0.299f * r2 + 0.587f * q2 + 0.114f * b2) * 255.0f;
    g1[(size_t)b * HWSZ + idx] = lum1;
    g2[(size_t)b * HWSZ + idx] = lum2;

    float u = fl[idx], v = fl[HWSZ + idx];
    float du = u - tg[idx], dv = v - tg[HWSZ + idx];
    float epe = sqrtf(du * du + dv * dv);

    float sx = 0.0f, sy = 0.0f;
    if (x < WW - 1) {
        float ad = fabsf(r1 - i1[idx + 1]) + fabsf(q1 - i1[HWSZ + idx + 1]) + fabsf(b1 - i1[2 * HWSZ + idx + 1]);
        float wx = __expf(-4.0f / 3.0f * ad);
        float d0 = u - fl[idx + 1], d1 = v - fl[HWSZ + idx + 1];
        sx = wx * (__powf(d0 * d0 + 1e-6f, 0.45f) + __powf(d1 * d1 + 1e-6f, 0.45f));
    }
    if (y < HH - 1) {
        float ad = fabsf(r1 - i1[idx + WW]) + fabsf(q1 - i1[HWSZ + idx + WW]) + fabsf(b1 - i1[2 * HWSZ + idx + WW]);
        float wy = __expf(-4.0f / 3.0f * ad);
        float d0 = u - fl[idx + WW], d1 = v - fl[HWSZ + idx + WW];
        sy = wy * (__powf(d0 * d0 + 1e-6f, 0.45f) + __powf(d1 * d1 + 1e-6f, 0.45f));
    }

    // reduce: each threadIdx.y row is exactly one wave (64 lanes)
    #pragma unroll
    for (int off = 32; off; off >>= 1) {
        epe += __shfl_down(epe, off);
        sx  += __shfl_down(sx, off);
        sy  += __shfl_down(sy, off);
    }
    __shared__ float red[3][4];
    if (threadIdx.x == 0) {
        red[0][threadIdx.y] = sx;
        red[1][threadIdx.y] = sy;
        red[2][threadIdx.y] = epe;
    }
    __syncthreads();
    if (threadIdx.x == 0 && threadIdx.y == 0) {
        atomicAdd(acc + 1, red[0][0] + red[0][1] + red[0][2] + red[0][3]);
        atomicAdd(acc + 2, red[1][0] + red[1][1] + red[1][2] + red[1][3]);
        atomicAdd(acc + 3, red[2][0] + red[2][1] + red[2][2] + red[2][3]);
    }
}

__global__ __launch_bounds__(256) void k_census(
    const float* __restrict__ flow,
    const float* __restrict__ g1, const float* __restrict__ g2,
    float* __restrict__ acc)
{
    __shared__ float t1s[HY][HX];
    __shared__ float t2s[HY][HX];
    __shared__ unsigned char mks[HY][HX];

    const int b = blockIdx.z;
    const int x0 = CR + blockIdx.x * TX;
    const int y0 = CR + blockIdx.y * TY;
    const float* g1b = g1 + (size_t)b * HWSZ;
    const float* g2b = g2 + (size_t)b * HWSZ;
    const float* fl = flow + (size_t)b * 2 * HWSZ;
    const int tid = threadIdx.x;

    // stage halo tile: g1, warped g2 (computed on the fly), border mask
    for (int i = tid; i < HY * HX; i += 256) {
        int ly = i / HX, lx = i - ly * HX;
        int gx = x0 - CR + lx; if (gx > WW - 1) gx = WW - 1;
        int gy = y0 - CR + ly; if (gy > HH - 1) gy = HH - 1;
        int gidx = gy * WW + gx;
        t1s[ly][lx] = g1b[gidx];
        float u = fl[gidx], v = fl[HWSZ + gidx];
        float xx = (float)gx + u, yy = (float)gy + v;
        float fx = floorf(xx), fy = floorf(yy);
        float wx = xx - fx, wy = yy - fy;
        int xi0 = (int)fx; xi0 = xi0 < 0 ? 0 : (xi0 > WW - 1 ? WW - 1 : xi0);
        int xi1 = xi0 + 1 > WW - 1 ? WW - 1 : xi0 + 1;
        int yi0 = (int)fy; yi0 = yi0 < 0 ? 0 : (yi0 > HH - 1 ? HH - 1 : yi0);
        int yi1 = yi0 + 1 > HH - 1 ? HH - 1 : yi0 + 1;
        float v00 = g2b[yi0 * WW + xi0], v01 = g2b[yi0 * WW + xi1];
        float v10 = g2b[yi1 * WW + xi0], v11 = g2b[yi1 * WW + xi1];
        t2s[ly][lx] = v00 * ((1.0f - wx) * (1.0f - wy)) + v01 * (wx * (1.0f - wy))
                    + v10 * ((1.0f - wx) * wy) + v11 * (wx * wy);
        mks[ly][lx] = (unsigned char)((xx >= 0.0f) && (xx <= (float)(WW - 1)) &&
                                      (yy >= 0.0f) && (yy <= (float)(HH - 1)));
    }
    __syncthreads();

    const int lx = tid & 63;
    const int lyb = tid >> 6;
    float sum = 0.0f;
    #pragma unroll
    for (int j = 0; j < 4; j++) {
        const int ly = j * 4 + lyb;
        const int cx = x0 + lx, cy = y0 + ly;
        const bool valid = (cx <= WW - 1 - CR) && (cy <= HH - 1 - CR);
        const int hx = lx + CR, hy = ly + CR;
        const float c1 = t1s[hy][hx];
        const float c2 = t2s[hy][hx];
        float dist = 0.0f;
        #pragma unroll
        for (int dy = -CR; dy <= CR; dy++) {
            #pragma unroll
            for (int dx = -CR; dx <= CR; dx++) {
                if (dx == 0 && dy == 0) continue;
                float d1 = t1s[hy + dy][hx + dx] - c1;
                float d2 = t2s[hy + dy][hx + dx] - c2;
                float t1 = d1 * __builtin_amdgcn_rsqf(fmaf(d1, d1, 0.81f));
                float t2 = d2 * __builtin_amdgcn_rsqf(fmaf(d2, d2, 0.81f));
                float dd = t1 - t2;
                float s = dd * dd;
                dist = fmaf(s, __builtin_amdgcn_rcpf(0.1f + s), dist);
            }
        }
        if (valid && mks[hy][hx]) {
            sum += __powf(fmaf(dist, dist, 1e-6f), 0.45f);
        }
    }

    #pragma unroll
    for (int off = 32; off; off >>= 1) sum += __shfl_down(sum, off);
    __shared__ float rs[4];
    if ((tid & 63) == 0) rs[tid >> 6] = sum;
    __syncthreads();
    if (tid == 0) atomicAdd(acc + 0, rs[0] + rs[1] + rs[2] + rs[3]);
}

__global__ void k_final(const float* __restrict__ acc, float* __restrict__ out)
{
    if (threadIdx.x == 0) {
        float census = acc[0] / (float)NPIX;
        float mx = acc[1] / (float)((size_t)BB * 2 * HH * (WW - 1));
        float my = acc[2] / (float)((size_t)BB * 2 * (HH - 1) * WW);
        float epe = acc[3] / (float)NPIX;
        out[0] = census + 0.5f * (mx + my);
        out[1] = epe;
    }
}

extern "C" void kernel_launch(void* const* d_in, const int* in_sizes, int n_in,
                              void* d_out, int out_size, void* d_ws, size_t ws_size,
                              hipStream_t stream) {
    const float* flow   = (const float*)d_in[0];
    const float* target = (const float*)d_in[1];
    const float* img1   = (const float*)d_in[2];
    const float* img2   = (const float*)d_in[3];
    float* out = (float*)d_out;
    float* acc = (float*)d_ws;                       // 4 floats
    float* g1 = (float*)((char*)d_ws + 256);
    float* g2 = g1 + (size_t)NPIX;

    hipMemsetAsync(acc, 0, 16, stream);

    dim3 b1(64, 4, 1);
    dim3 gr1(WW / 64, HH / 4, BB);
    k_prep<<<gr1, b1, 0, stream>>>(flow, target, img1, img2, g1, g2, acc);

    dim3 gr2((WW - 2 * CR + TX - 1) / TX, (HH - 2 * CR + TY - 1) / TY, BB);
    k_census<<<gr2, dim3(256, 1, 1), 0, stream>>>(flow, g1, g2, acc);

    k_final<<<1, 64, 0, stream>>>(acc, out);
}

// Round 2
// 258.043 us; speedup vs baseline: 3.0109x; 3.0109x over previous
//
#include <hip/hip_runtime.h>
#include <math.h>

#define BB 8
#define HH 448
#define WW 1024
#define HWSZ (HH*WW)
#define NPIX (BB*HH*WW)
#define CR 3
#define TX 64
#define TY 16
#define HX (TX+2*CR)   // 70
#define HY (TY+2*CR)   // 22
#define NB1 (HH*BB)                      // 3584 k_prep blocks
#define NB2 (16*28*BB)                   // 3584 k_census blocks

__device__ __forceinline__ float pen45(float dd) {   // dd = d*d + eps, dd > 0
    return __expf(0.45f * __logf(dd));               // (dd)^0.45 via native log/exp
}

// ws layout: part_sx[NB1] | part_sy[NB1] | part_epe[NB1] | part_cen[NB2] | (pad to 64KB) | g1[NPIX] | g2[NPIX]

__global__ __launch_bounds__(256) void k_prep(
    const float* __restrict__ flow, const float* __restrict__ target,
    const float* __restrict__ img1, const float* __restrict__ img2,
    float* __restrict__ g1, float* __restrict__ g2,
    float* __restrict__ part_sx, float* __restrict__ part_sy, float* __restrict__ part_epe)
{
    const int tid = threadIdx.x;          // 0..255
    const int y = blockIdx.x;             // 0..447
    const int b = blockIdx.y;             // 0..7
    const int x = tid * 4;
    const int idx = y * WW + x;
    const float* i1r = img1 + (size_t)b * 3 * HWSZ;
    const float* i1g = i1r + HWSZ;
    const float* i1b = i1r + 2 * HWSZ;
    const float* i2r = img2 + (size_t)b * 3 * HWSZ;
    const float* i2g = i2r + HWSZ;
    const float* i2b = i2r + 2 * HWSZ;
    const float* fu = flow + (size_t)b * 2 * HWSZ;
    const float* fv = fu + HWSZ;
    const float* tu = target + (size_t)b * 2 * HWSZ;
    const float* tv = tu + HWSZ;

    float4 a1r = *(const float4*)(i1r + idx);
    float4 a1g = *(const float4*)(i1g + idx);
    float4 a1b = *(const float4*)(i1b + idx);
    float4 a2r = *(const float4*)(i2r + idx);
    float4 a2g = *(const float4*)(i2g + idx);
    float4 a2b = *(const float4*)(i2b + idx);
    float4 au  = *(const float4*)(fu + idx);
    float4 av  = *(const float4*)(fv + idx);
    float4 atu = *(const float4*)(tu + idx);
    float4 atv = *(const float4*)(tv + idx);

    // x-neighbor scalars (element x+4); tid==255 loads a dummy in-bounds value (masked)
    const int nf = (tid == 255) ? 3 : 4;
    float nr = i1r[idx + nf], ng = i1g[idx + nf], nb = i1b[idx + nf];
    float nu = fu[idx + nf],  nv = fv[idx + nf];

    // grayscale + store
    float4 l1, l2;
    l1.x = (0.299f*a1r.x + 0.587f*a1g.x + 0.114f*a1b.x) * 255.0f;
    l1.y = (0.299f*a1r.y + 0.587f*a1g.y + 0.114f*a1b.y) * 255.0f;
    l1.z = (0.299f*a1r.z + 0.587f*a1g.z + 0.114f*a1b.z) * 255.0f;
    l1.w = (0.299f*a1r.w + 0.587f*a1g.w + 0.114f*a1b.w) * 255.0f;
    l2.x = (0.299f*a2r.x + 0.587f*a2g.x + 0.114f*a2b.x) * 255.0f;
    l2.y = (0.299f*a2r.y + 0.587f*a2g.y + 0.114f*a2b.y) * 255.0f;
    l2.z = (0.299f*a2r.z + 0.587f*a2g.z + 0.114f*a2b.z) * 255.0f;
    l2.w = (0.299f*a2r.w + 0.587f*a2g.w + 0.114f*a2b.w) * 255.0f;
    *(float4*)(g1 + (size_t)b * HWSZ + idx) = l1;
    *(float4*)(g2 + (size_t)b * HWSZ + idx) = l2;

    // EPE
    float A1r[5] = {a1r.x, a1r.y, a1r.z, a1r.w, nr};
    float A1g[5] = {a1g.x, a1g.y, a1g.z, a1g.w, ng};
    float A1b[5] = {a1b.x, a1b.y, a1b.z, a1b.w, nb};
    float FU[5]  = {au.x, au.y, au.z, au.w, nu};
    float FV[5]  = {av.x, av.y, av.z, av.w, nv};
    float TU[4]  = {atu.x, atu.y, atu.z, atu.w};
    float TV[4]  = {atv.x, atv.y, atv.z, atv.w};

    float ep = 0.0f, sx = 0.0f, sy = 0.0f;
    #pragma unroll
    for (int k = 0; k < 4; k++) {
        float du = FU[k] - TU[k], dv = FV[k] - TV[k];
        ep += sqrtf(du * du + dv * dv);
        float ad = fabsf(A1r[k] - A1r[k+1]) + fabsf(A1g[k] - A1g[k+1]) + fabsf(A1b[k] - A1b[k+1]);
        float wx = __expf(-(4.0f / 3.0f) * ad);
        float d0 = FU[k] - FU[k+1], d1 = FV[k] - FV[k+1];
        float t = wx * (pen45(fmaf(d0, d0, 1e-6f)) + pen45(fmaf(d1, d1, 1e-6f)));
        if (x + k < WW - 1) sx += t;
    }

    if (y < HH - 1) {
        float4 b1r = *(const float4*)(i1r + idx + WW);
        float4 b1g = *(const float4*)(i1g + idx + WW);
        float4 b1b = *(const float4*)(i1b + idx + WW);
        float4 bu  = *(const float4*)(fu + idx + WW);
        float4 bv  = *(const float4*)(fv + idx + WW);
        float B1r[4] = {b1r.x, b1r.y, b1r.z, b1r.w};
        float B1g[4] = {b1g.x, b1g.y, b1g.z, b1g.w};
        float B1b[4] = {b1b.x, b1b.y, b1b.z, b1b.w};
        float BU[4]  = {bu.x, bu.y, bu.z, bu.w};
        float BV[4]  = {bv.x, bv.y, bv.z, bv.w};
        #pragma unroll
        for (int k = 0; k < 4; k++) {
            float ad = fabsf(A1r[k] - B1r[k]) + fabsf(A1g[k] - B1g[k]) + fabsf(A1b[k] - B1b[k]);
            float wy = __expf(-(4.0f / 3.0f) * ad);
            float d0 = FU[k] - BU[k], d1 = FV[k] - BV[k];
            sy += wy * (pen45(fmaf(d0, d0, 1e-6f)) + pen45(fmaf(d1, d1, 1e-6f)));
        }
    }

    #pragma unroll
    for (int off = 32; off; off >>= 1) {
        ep += __shfl_down(ep, off);
        sx += __shfl_down(sx, off);
        sy += __shfl_down(sy, off);
    }
    __shared__ float red[3][4];
    const int lane = tid & 63, wid = tid >> 6;
    if (lane == 0) { red[0][wid] = sx; red[1][wid] = sy; red[2][wid] = ep; }
    __syncthreads();
    if (tid == 0) {
        const int bid = b * HH + y;
        part_sx[bid]  = red[0][0] + red[0][1] + red[0][2] + red[0][3];
        part_sy[bid]  = red[1][0] + red[1][1] + red[1][2] + red[1][3];
        part_epe[bid] = red[2][0] + red[2][1] + red[2][2] + red[2][3];
    }
}

__global__ __launch_bounds__(256) void k_census(
    const float* __restrict__ flow,
    const float* __restrict__ g1, const float* __restrict__ g2,
    float* __restrict__ part_cen)
{
    __shared__ float t1s[HY][HX];
    __shared__ float t2s[HY][HX];
    __shared__ unsigned char mks[HY][HX];

    const int b = blockIdx.z;
    const int x0 = CR + blockIdx.x * TX;
    const int y0 = CR + blockIdx.y * TY;
    const float* g1b = g1 + (size_t)b * HWSZ;
    const float* g2b = g2 + (size_t)b * HWSZ;
    const float* fl = flow + (size_t)b * 2 * HWSZ;
    const int tid = threadIdx.x;

    for (int i = tid; i < HY * HX; i += 256) {
        int ly = i / HX, lx = i - ly * HX;
        int gx = x0 - CR + lx; if (gx > WW - 1) gx = WW - 1;
        int gy = y0 - CR + ly; if (gy > HH - 1) gy = HH - 1;
        int gidx = gy * WW + gx;
        t1s[ly][lx] = g1b[gidx];
        float u = fl[gidx], v = fl[HWSZ + gidx];
        float xx = (float)gx + u, yy = (float)gy + v;
        float fx = floorf(xx), fy = floorf(yy);
        float wx = xx - fx, wy = yy - fy;
        int xi0 = (int)fx; xi0 = xi0 < 0 ? 0 : (xi0 > WW - 1 ? WW - 1 : xi0);
        int xi1 = xi0 + 1 > WW - 1 ? WW - 1 : xi0 + 1;
        int yi0 = (int)fy; yi0 = yi0 < 0 ? 0 : (yi0 > HH - 1 ? HH - 1 : yi0);
        int yi1 = yi0 + 1 > HH - 1 ? HH - 1 : yi0 + 1;
        float v00 = g2b[yi0 * WW + xi0], v01 = g2b[yi0 * WW + xi1];
        float v10 = g2b[yi1 * WW + xi0], v11 = g2b[yi1 * WW + xi1];
        t2s[ly][lx] = v00 * ((1.0f - wx) * (1.0f - wy)) + v01 * (wx * (1.0f - wy))
                    + v10 * ((1.0f - wx) * wy) + v11 * (wx * wy);
        mks[ly][lx] = (unsigned char)((xx >= 0.0f) && (xx <= (float)(WW - 1)) &&
                                      (yy >= 0.0f) && (yy <= (float)(HH - 1)));
    }
    __syncthreads();

    const int lx = tid & 63;
    const int lyb = tid >> 6;
    float sum = 0.0f;
    #pragma unroll
    for (int j = 0; j < 4; j++) {
        const int ly = j * 4 + lyb;
        const int cx = x0 + lx, cy = y0 + ly;
        const bool valid = (cx <= WW - 1 - CR) && (cy <= HH - 1 - CR);
        const int hx = lx + CR, hy = ly + CR;
        const float c1 = t1s[hy][hx];
        const float c2 = t2s[hy][hx];
        float dist = 0.0f;
        #pragma unroll
        for (int dy = -CR; dy <= CR; dy++) {
            #pragma unroll
            for (int dx = -CR; dx <= CR; dx++) {
                if (dx == 0 && dy == 0) continue;
                float d1 = t1s[hy + dy][hx + dx] - c1;
                float d2 = t2s[hy + dy][hx + dx] - c2;
                float t1 = d1 * __builtin_amdgcn_rsqf(fmaf(d1, d1, 0.81f));
                float t2 = d2 * __builtin_amdgcn_rsqf(fmaf(d2, d2, 0.81f));
                float dd = t1 - t2;
                float s = dd * dd;
                dist = fmaf(s, __builtin_amdgcn_rcpf(0.1f + s), dist);
            }
        }
        if (valid && mks[hy][hx]) {
            sum += pen45(fmaf(dist, dist, 1e-6f));
        }
    }

    #pragma unroll
    for (int off = 32; off; off >>= 1) sum += __shfl_down(sum, off);
    __shared__ float rs[4];
    if ((tid & 63) == 0) rs[tid >> 6] = sum;
    __syncthreads();
    if (tid == 0) {
        const int bid = (b * gridDim.y + blockIdx.y) * gridDim.x + blockIdx.x;
        part_cen[bid] = rs[0] + rs[1] + rs[2] + rs[3];
    }
}

__global__ __launch_bounds__(256) void k_final(
    const float* __restrict__ part_sx, const float* __restrict__ part_sy,
    const float* __restrict__ part_epe, const float* __restrict__ part_cen,
    float* __restrict__ out)
{
    const int tid = threadIdx.x;
    float sx = 0.f, sy = 0.f, ep = 0.f, cn = 0.f;
    for (int i = tid; i < NB1; i += 256) {
        sx += part_sx[i]; sy += part_sy[i]; ep += part_epe[i];
    }
    for (int i = tid; i < NB2; i += 256) cn += part_cen[i];
    #pragma unroll
    for (int off = 32; off; off >>= 1) {
        sx += __shfl_down(sx, off); sy += __shfl_down(sy, off);
        ep += __shfl_down(ep, off); cn += __shfl_down(cn, off);
    }
    __shared__ float r[4][4];
    const int lane = tid & 63, wid = tid >> 6;
    if (lane == 0) { r[0][wid] = sx; r[1][wid] = sy; r[2][wid] = ep; r[3][wid] = cn; }
    __syncthreads();
    if (tid == 0) {
        sx = r[0][0] + r[0][1] + r[0][2] + r[0][3];
        sy = r[1][0] + r[1][1] + r[1][2] + r[1][3];
        ep = r[2][0] + r[2][1] + r[2][2] + r[2][3];
        cn = r[3][0] + r[3][1] + r[3][2] + r[3][3];
        float census = cn / (float)NPIX;
        float mx = sx / (float)((size_t)BB * 2 * HH * (WW - 1));
        float my = sy / (float)((size_t)BB * 2 * (HH - 1) * WW);
        out[0] = census + 0.5f * (mx + my);
        out[1] = ep / (float)NPIX;
    }
}

extern "C" void kernel_launch(void* const* d_in, const int* in_sizes, int n_in,
                              void* d_out, int out_size, void* d_ws, size_t ws_size,
                              hipStream_t stream) {
    const float* flow   = (const float*)d_in[0];
    const float* target = (const float*)d_in[1];
    const float* img1   = (const float*)d_in[2];
    const float* img2   = (const float*)d_in[3];
    float* out = (float*)d_out;

    float* part_sx  = (float*)d_ws;
    float* part_sy  = part_sx + NB1;
    float* part_epe = part_sy + NB1;
    float* part_cen = part_epe + NB1;
    float* g1 = (float*)((char*)d_ws + 65536);
    float* g2 = g1 + (size_t)NPIX;

    dim3 gr1(HH, BB, 1);
    k_prep<<<gr1, dim3(256, 1, 1), 0, stream>>>(flow, target, img1, img2, g1, g2,
                                                part_sx, part_sy, part_epe);

    dim3 gr2((WW - 2 * CR + TX - 1) / TX, (HH - 2 * CR + TY - 1) / TY, BB);
    k_census<<<gr2, dim3(256, 1, 1), 0, stream>>>(flow, g1, g2, part_cen);

    k_final<<<1, dim3(256, 1, 1), 0, stream>>>(part_sx, part_sy, part_epe, part_cen, out);
}

// Round 5
// 254.168 us; speedup vs baseline: 3.0568x; 1.0152x over previous
//
#include <hip/hip_runtime.h>
#include <math.h>

#define BB 8
#define HH 448
#define WW 1024
#define HWSZ (HH*WW)
#define NPIX (BB*HH*WW)
#define CR 3
#define TX 64
#define TY 16
#define HX (TX+2*CR)   // 70
#define HXP 72         // padded LDS row stride (multiple of 4 for b128 alignment)
#define HY (TY+2*CR)   // 22
#define NB1 (HH*BB)                      // 3584 k_prep blocks
#define NB2 (16*28*BB)                   // 3584 k_census blocks

__device__ __forceinline__ float pen45(float dd) {   // dd = d*d + eps, dd > 0
    return __expf(0.45f * __logf(dd));               // (dd)^0.45 via native log/exp
}

// ws layout: part_sx[NB1] | part_sy[NB1] | part_epe[NB1] | part_cen[NB2] | (pad to 64KB) | g1[NPIX] | g2[NPIX]

__global__ __launch_bounds__(256) void k_prep(
    const float* __restrict__ flow, const float* __restrict__ target,
    const float* __restrict__ img1, const float* __restrict__ img2,
    float* __restrict__ g1, float* __restrict__ g2,
    float* __restrict__ part_sx, float* __restrict__ part_sy, float* __restrict__ part_epe)
{
    const int tid = threadIdx.x;          // 0..255
    const int y = blockIdx.x;             // 0..447
    const int b = blockIdx.y;             // 0..7
    const int x = tid * 4;
    const int idx = y * WW + x;
    const float* i1r = img1 + (size_t)b * 3 * HWSZ;
    const float* i1g = i1r + HWSZ;
    const float* i1b = i1r + 2 * HWSZ;
    const float* i2r = img2 + (size_t)b * 3 * HWSZ;
    const float* i2g = i2r + HWSZ;
    const float* i2b = i2r + 2 * HWSZ;
    const float* fu = flow + (size_t)b * 2 * HWSZ;
    const float* fv = fu + HWSZ;
    const float* tu = target + (size_t)b * 2 * HWSZ;
    const float* tv = tu + HWSZ;

    float4 a1r = *(const float4*)(i1r + idx);
    float4 a1g = *(const float4*)(i1g + idx);
    float4 a1b = *(const float4*)(i1b + idx);
    float4 a2r = *(const float4*)(i2r + idx);
    float4 a2g = *(const float4*)(i2g + idx);
    float4 a2b = *(const float4*)(i2b + idx);
    float4 au  = *(const float4*)(fu + idx);
    float4 av  = *(const float4*)(fv + idx);
    float4 atu = *(const float4*)(tu + idx);
    float4 atv = *(const float4*)(tv + idx);

    // x-neighbor scalars (element x+4); tid==255 loads a dummy in-bounds value (masked)
    const int nf = (tid == 255) ? 3 : 4;
    float nr = i1r[idx + nf], ng = i1g[idx + nf], nb = i1b[idx + nf];
    float nu = fu[idx + nf],  nv = fv[idx + nf];

    // grayscale + store
    float4 l1, l2;
    l1.x = (0.299f*a1r.x + 0.587f*a1g.x + 0.114f*a1b.x) * 255.0f;
    l1.y = (0.299f*a1r.y + 0.587f*a1g.y + 0.114f*a1b.y) * 255.0f;
    l1.z = (0.299f*a1r.z + 0.587f*a1g.z + 0.114f*a1b.z) * 255.0f;
    l1.w = (0.299f*a1r.w + 0.587f*a1g.w + 0.114f*a1b.w) * 255.0f;
    l2.x = (0.299f*a2r.x + 0.587f*a2g.x + 0.114f*a2b.x) * 255.0f;
    l2.y = (0.299f*a2r.y + 0.587f*a2g.y + 0.114f*a2b.y) * 255.0f;
    l2.z = (0.299f*a2r.z + 0.587f*a2g.z + 0.114f*a2b.z) * 255.0f;
    l2.w = (0.299f*a2r.w + 0.587f*a2g.w + 0.114f*a2b.w) * 255.0f;
    *(float4*)(g1 + (size_t)b * HWSZ + idx) = l1;
    *(float4*)(g2 + (size_t)b * HWSZ + idx) = l2;

    float A1r[5] = {a1r.x, a1r.y, a1r.z, a1r.w, nr};
    float A1g[5] = {a1g.x, a1g.y, a1g.z, a1g.w, ng};
    float A1b[5] = {a1b.x, a1b.y, a1b.z, a1b.w, nb};
    float FU[5]  = {au.x, au.y, au.z, au.w, nu};
    float FV[5]  = {av.x, av.y, av.z, av.w, nv};
    float TU[4]  = {atu.x, atu.y, atu.z, atu.w};
    float TV[4]  = {atv.x, atv.y, atv.z, atv.w};

    float ep = 0.0f, sx = 0.0f, sy = 0.0f;
    #pragma unroll
    for (int k = 0; k < 4; k++) {
        float du = FU[k] - TU[k], dv = FV[k] - TV[k];
        ep += sqrtf(du * du + dv * dv);
        float ad = fabsf(A1r[k] - A1r[k+1]) + fabsf(A1g[k] - A1g[k+1]) + fabsf(A1b[k] - A1b[k+1]);
        float wx = __expf(-(4.0f / 3.0f) * ad);
        float d0 = FU[k] - FU[k+1], d1 = FV[k] - FV[k+1];
        float t = wx * (pen45(fmaf(d0, d0, 1e-6f)) + pen45(fmaf(d1, d1, 1e-6f)));
        if (x + k < WW - 1) sx += t;
    }

    if (y < HH - 1) {
        float4 b1r = *(const float4*)(i1r + idx + WW);
        float4 b1g = *(const float4*)(i1g + idx + WW);
        float4 b1b = *(const float4*)(i1b + idx + WW);
        float4 bu  = *(const float4*)(fu + idx + WW);
        float4 bv  = *(const float4*)(fv + idx + WW);
        float B1r[4] = {b1r.x, b1r.y, b1r.z, b1r.w};
        float B1g[4] = {b1g.x, b1g.y, b1g.z, b1g.w};
        float B1b[4] = {b1b.x, b1b.y, b1b.z, b1b.w};
        float BU[4]  = {bu.x, bu.y, bu.z, bu.w};
        float BV[4]  = {bv.x, bv.y, bv.z, bv.w};
        #pragma unroll
        for (int k = 0; k < 4; k++) {
            float ad = fabsf(A1r[k] - B1r[k]) + fabsf(A1g[k] - B1g[k]) + fabsf(A1b[k] - B1b[k]);
            float wy = __expf(-(4.0f / 3.0f) * ad);
            float d0 = FU[k] - BU[k], d1 = FV[k] - BV[k];
            sy += wy * (pen45(fmaf(d0, d0, 1e-6f)) + pen45(fmaf(d1, d1, 1e-6f)));
        }
    }

    #pragma unroll
    for (int off = 32; off; off >>= 1) {
        ep += __shfl_down(ep, off);
        sx += __shfl_down(sx, off);
        sy += __shfl_down(sy, off);
    }
    __shared__ float red[3][4];
    const int lane = tid & 63, wid = tid >> 6;
    if (lane == 0) { red[0][wid] = sx; red[1][wid] = sy; red[2][wid] = ep; }
    __syncthreads();
    if (tid == 0) {
        const int bid = b * HH + y;
        part_sx[bid]  = red[0][0] + red[0][1] + red[0][2] + red[0][3];
        part_sy[bid]  = red[1][0] + red[1][1] + red[1][2] + red[1][3];
        part_epe[bid] = red[2][0] + red[2][1] + red[2][2] + red[2][3];
    }
}

__global__ __launch_bounds__(256) void k_census(
    const float* __restrict__ flow,
    const float* __restrict__ g1, const float* __restrict__ g2,
    float* __restrict__ part_cen)
{
    __shared__ float t1s[HY][HXP];
    __shared__ float t2s[HY][HXP];
    __shared__ float mks[TY][TX];   // border mask, centers only

    const int b = blockIdx.z;
    const int x0 = CR + blockIdx.x * TX;
    const int y0 = CR + blockIdx.y * TY;
    const float* g1b = g1 + (size_t)b * HWSZ;
    const float* g2b = g2 + (size_t)b * HWSZ;
    const float* fl = flow + (size_t)b * 2 * HWSZ;
    const int tid = threadIdx.x;

    // stage halo tile: g1, warped g2 (computed on the fly), center border-mask
    for (int i = tid; i < HY * HX; i += 256) {
        int ly = i / HX, lx = i - ly * HX;
        int gx = x0 - CR + lx; if (gx > WW - 1) gx = WW - 1;
        int gy = y0 - CR + ly; if (gy > HH - 1) gy = HH - 1;
        int gidx = gy * WW + gx;
        t1s[ly][lx] = g1b[gidx];
        float u = fl[gidx], v = fl[HWSZ + gidx];
        float xx = (float)gx + u, yy = (float)gy + v;
        float fx = floorf(xx), fy = floorf(yy);
        float wx = xx - fx, wy = yy - fy;
        int xi0 = (int)fx; xi0 = xi0 < 0 ? 0 : (xi0 > WW - 1 ? WW - 1 : xi0);
        int xi1 = xi0 + 1 > WW - 1 ? WW - 1 : xi0 + 1;
        int yi0 = (int)fy; yi0 = yi0 < 0 ? 0 : (yi0 > HH - 1 ? HH - 1 : yi0);
        int yi1 = yi0 + 1 > HH - 1 ? HH - 1 : yi0 + 1;
        float v00 = g2b[yi0 * WW + xi0], v01 = g2b[yi0 * WW + xi1];
        float v10 = g2b[yi1 * WW + xi0], v11 = g2b[yi1 * WW + xi1];
        t2s[ly][lx] = v00 * ((1.0f - wx) * (1.0f - wy)) + v01 * (wx * (1.0f - wy))
                    + v10 * ((1.0f - wx) * wy) + v11 * (wx * wy);
        if (lx >= CR && lx < CR + TX && ly >= CR && ly < CR + TY)
            mks[ly - CR][lx - CR] = (float)((xx >= 0.0f) && (xx <= (float)(WW - 1)) &&
                                            (yy >= 0.0f) && (yy <= (float)(HH - 1)));
    }
    __syncthreads();

    // each thread: 4 consecutive-x centers in one row
    const int txg = tid & 15;          // x group (16 groups * 4 px = 64)
    const int ty  = tid >> 4;          // 0..15
    const int lxb = txg * 4;           // row-local base; centers at lxb+CR+k
    const int rowc = ty + CR;

    float dist[4] = {0.f, 0.f, 0.f, 0.f};
    float c1[4], c2[4];

#define LOADROW(ROW, V1, V2)                                            \
    float V1[12], V2[12];                                               \
    {                                                                   \
        float4 _a0 = *(const float4*)&t1s[ROW][lxb];                    \
        float4 _a1 = *(const float4*)&t1s[ROW][lxb + 4];                \
        float4 _a2 = *(const float4*)&t1s[ROW][lxb + 8];                \
        float4 _b0 = *(const float4*)&t2s[ROW][lxb];                    \
        float4 _b1 = *(const float4*)&t2s[ROW][lxb + 4];                \
        float4 _b2 = *(const float4*)&t2s[ROW][lxb + 8];                \
        V1[0]=_a0.x; V1[1]=_a0.y; V1[2]=_a0.z; V1[3]=_a0.w;             \
        V1[4]=_a1.x; V1[5]=_a1.y; V1[6]=_a1.z; V1[7]=_a1.w;             \
        V1[8]=_a2.x; V1[9]=_a2.y; V1[10]=_a2.z; V1[11]=_a2.w;           \
        V2[0]=_b0.x; V2[1]=_b0.y; V2[2]=_b0.z; V2[3]=_b0.w;             \
        V2[4]=_b1.x; V2[5]=_b1.y; V2[6]=_b1.z; V2[7]=_b1.w;             \
        V2[8]=_b2.x; V2[9]=_b2.y; V2[10]=_b2.z; V2[11]=_b2.w;           \
    }

#define PAIR(V1, V2, K, DX)                                              \
    {                                                                    \
        float _d1 = V1[3 + (K) + (DX)] - c1[K];                          \
        float _d2 = V2[3 + (K) + (DX)] - c2[K];                          \
        float _u1 = _d1 * __builtin_amdgcn_rsqf(fmaf(_d1, _d1, 0.81f));  \
        float _u2 = _d2 * __builtin_amdgcn_rsqf(fmaf(_d2, _d2, 0.81f));  \
        float _dd = _u1 - _u2;                                           \
        float _s = _dd * _dd;                                            \
        dist[K] = fmaf(_s, __builtin_amdgcn_rcpf(0.1f + _s), dist[K]);   \
    }

    // center row first (extract centers, then its 6 dx-neighbors)
    {
        LOADROW(rowc, v1, v2)
        #pragma unroll
        for (int k = 0; k < 4; k++) { c1[k] = v1[3 + k]; c2[k] = v2[3 + k]; }
        #pragma unroll
        for (int k = 0; k < 4; k++) {
            #pragma unroll
            for (int dx = -CR; dx <= CR; dx++) {
                if (dx == 0) continue;
                PAIR(v1, v2, k, dx)
            }
        }
    }
    // other 6 rows, all 7 dx
    #pragma unroll
    for (int dyi = 0; dyi < 6; dyi++) {
        const int dy = (dyi < 3) ? (dyi - 3) : (dyi - 2);   // -3,-2,-1,1,2,3
        const int row = rowc + dy;
        LOADROW(row, v1, v2)
        #pragma unroll
        for (int k = 0; k < 4; k++) {
            #pragma unroll
            for (int dx = -CR; dx <= CR; dx++) {
                PAIR(v1, v2, k, dx)
            }
        }
    }

    float sum = 0.0f;
    const int cy = y0 + ty;
    const float4 mk = *(const float4*)&mks[ty][lxb];
    const float mka[4] = {mk.x, mk.y, mk.z, mk.w};
    #pragma unroll
    for (int k = 0; k < 4; k++) {
        const int cx = x0 + lxb + k;
        const bool valid = (cx <= WW - 1 - CR) && (cy <= HH - 1 - CR);
        float m = valid ? mka[k] : 0.0f;
        sum += m * pen45(fmaf(dist[k], dist[k], 1e-6f));
    }

    #pragma unroll
    for (int off = 32; off; off >>= 1) sum += __shfl_down(sum, off);
    __shared__ float rs[4];
    if ((tid & 63) == 0) rs[tid >> 6] = sum;
    __syncthreads();
    if (tid == 0) {
        const int bid = (b * gridDim.y + blockIdx.y) * gridDim.x + blockIdx.x;
        part_cen[bid] = rs[0] + rs[1] + rs[2] + rs[3];
    }
#undef LOADROW
#undef PAIR
}

__global__ __launch_bounds__(256) void k_final(
    const float* __restrict__ part_sx, const float* __restrict__ part_sy,
    const float* __restrict__ part_epe, const float* __restrict__ part_cen,
    float* __restrict__ out)
{
    const int tid = threadIdx.x;
    float sx = 0.f, sy = 0.f, ep = 0.f, cn = 0.f;
    for (int i = tid; i < NB1; i += 256) {
        sx += part_sx[i]; sy += part_sy[i]; ep += part_epe[i];
    }
    for (int i = tid; i < NB2; i += 256) cn += part_cen[i];
    #pragma unroll
    for (int off = 32; off; off >>= 1) {
        sx += __shfl_down(sx, off); sy += __shfl_down(sy, off);
        ep += __shfl_down(ep, off); cn += __shfl_down(cn, off);
    }
    __shared__ float r[4][4];
    const int lane = tid & 63, wid = tid >> 6;
    if (lane == 0) { r[0][wid] = sx; r[1][wid] = sy; r[2][wid] = ep; r[3][wid] = cn; }
    __syncthreads();
    if (tid == 0) {
        sx = r[0][0] + r[0][1] + r[0][2] + r[0][3];
        sy = r[1][0] + r[1][1] + r[1][2] + r[1][3];
        ep = r[2][0] + r[2][1] + r[2][2] + r[2][3];
        cn = r[3][0] + r[3][1] + r[3][2] + r[3][3];
        float census = cn / (float)NPIX;
        float mx = sx / (float)((size_t)BB * 2 * HH * (WW - 1));
        float my = sy / (float)((size_t)BB * 2 * (HH - 1) * WW);
        out[0] = census + 0.5f * (mx + my);
        out[1] = ep / (float)NPIX;
    }
}

extern "C" void kernel_launch(void* const* d_in, const int* in_sizes, int n_in,
                              void* d_out, int out_size, void* d_ws, size_t ws_size,
                              hipStream_t stream) {
    const float* flow   = (const float*)d_in[0];
    const float* target = (const float*)d_in[1];
    const float* img1   = (const float*)d_in[2];
    const float* img2   = (const float*)d_in[3];
    float* out = (float*)d_out;

    float* part_sx  = (float*)d_ws;
    float* part_sy  = part_sx + NB1;
    float* part_epe = part_sy + NB1;
    float* part_cen = part_epe + NB1;
    float* g1 = (float*)((char*)d_ws + 65536);
    float* g2 = g1 + (size_t)NPIX;

    dim3 gr1(HH, BB, 1);
    k_prep<<<gr1, dim3(256, 1, 1), 0, stream>>>(flow, target, img1, img2, g1, g2,
                                                part_sx, part_sy, part_epe);

    dim3 gr2((WW - 2 * CR + TX - 1) / TX, (HH - 2 * CR + TY - 1) / TY, BB);
    k_census<<<gr2, dim3(256, 1, 1), 0, stream>>>(flow, g1, g2, part_cen);

    k_final<<<1, dim3(256, 1, 1), 0, stream>>>(part_sx, part_sy, part_epe, part_cen, out);
}